// Round 6
// baseline (221.126 us; speedup 1.0000x reference)
//
#include <hip/hip_runtime.h>

// B=32, T=4096, D=512. out[b] = retrieved[b] @ W.T + bias where retrieved[b]
// is the LAST write row (order n = t*B + b) whose int32 hash equals query b's
// hash. Hash = (int)trunc of numpy-pairwise f32 sum of row*1000 — bit-exact
// reproduction verified R1-R5.
//
// R6: single fused stream+out kernel. Every block release-increments a done
// counter after its stream share; the Bv*8 out-blocks acquire-spin until
// done==gridDim.x then compute their (b, d-chunk). Deadlock-free: spinners
// are 256/2048 blocks, stream-only blocks always exit and free slots.
// Screen: order-free sum then one *1000 scale; sound error bound:
//   reorder <= ~1.0 (2e-6 * 6-sigma abs-sum ~490K) + scale-once <= ~0.05
//   + 1.0 trunc window => ~2.05; eps=4.0 is ~2x margin. Flagged rows (~0.4%)
// take the exact numpy-order LDS hash path.

constexpr int Dm = 512;
constexpr int LROW = 544; // padded: elem idx stored at idx + 8*(idx>>7)

typedef float nt_f4 __attribute__((ext_vector_type(4))); // builtin-compatible

// Exact numpy pairwise sum of 512 f32 (each *1000 in f32 first), by a 32-lane
// group. lane=(k<<3)|j; k=128-block, j=accumulator. Per block: r[j] sequential
// 16 terms; combine ((r0+r1)+(r2+r3))+((r4+r5)+(r6+r7)); blocks (p0+p1)+(p2+p3).
// Butterfly == numpy tree (f32 add commutative). Bit-exact (R1 verified).
__device__ __forceinline__ int hash_row_lds(const float* rowp, int lane) {
#pragma clang fp contract(off)
    int k = lane >> 3, j = lane & 7;
    const float* p = rowp + k * 136 + j;
    float r = p[0] * 1000.0f;
#pragma unroll
    for (int i = 1; i < 16; ++i) {
        float prod = p[8 * i] * 1000.0f;
        r = r + prod;
    }
    r = r + __shfl_xor(r, 1);
    r = r + __shfl_xor(r, 2);
    r = r + __shfl_xor(r, 4);
    r = r + __shfl_xor(r, 8);
    r = r + __shfl_xor(r, 16);
    return (int)r; // trunc toward zero
}

// 1 block, 1024 threads = 32 groups: all query hashes in ONE round.
// Also zeroes the done counter and best[].
__global__ __launch_bounds__(1024) void init_kernel(const float* __restrict__ x,
                                                    int* __restrict__ qh_i,
                                                    float* __restrict__ qh_f,
                                                    int* __restrict__ best,
                                                    int* __restrict__ done,
                                                    int Bv, int Tv) {
    __shared__ float slab[32][LROW];
    int tid = threadIdx.x, grp = tid >> 5, lane = tid & 31;
    if (tid < Bv) best[tid] = -1;
    if (tid == 0) *done = 0;
    bool a = grp < Bv;
    if (a) {
        const float* row = x + ((long)grp * Tv + (Tv - 1)) * Dm;
#pragma unroll
        for (int c = 0; c < 4; ++c)
            *reinterpret_cast<float4*>(&slab[grp][c * 136 + lane * 4]) =
                *reinterpret_cast<const float4*>(row + c * 128 + lane * 4);
    }
    __syncthreads();
    if (a) {
        int h = hash_row_lds(slab[grp], lane);
        if (lane == 0) { qh_i[grp] = h; qh_f[grp] = (float)h; }
    }
}

// Fused: wave-per-row streaming (each wave owns rpw contiguous memory-order
// rows; 2x1KB nontemporal loads, prefetch 1 row), then done-counter barrier,
// then out-blocks compute out[b][c*64 .. c*64+63].
__global__ __launch_bounds__(256, 8) void fused_kernel(const float* __restrict__ x,
                                                       const float* __restrict__ W,
                                                       const float* __restrict__ bias,
                                                       const int* __restrict__ qh_i,
                                                       const float* __restrict__ qh_f,
                                                       int* __restrict__ best,
                                                       int* __restrict__ done,
                                                       float* __restrict__ out,
                                                       int Bv, int Tv, int rpw) {
    __shared__ float slab[4][LROW];
    __shared__ int sbest;
    const int tid = threadIdx.x;
    const int wslab = tid >> 6;
    const int lane = tid & 63;
    const int Tm1 = Tv - 1;
    const long NR = (long)Bv * Tm1;

    int qi = (int)0x80000000;
    float qf = __builtin_inff();
    if (lane < Bv) { qi = qh_i[lane]; qf = qh_f[lane]; }

    const int wave_id = blockIdx.x * 4 + wslab;
    long r = (long)wave_id * rpw;
    const long rend = min(r + rpw, NR);

    if (r < rend) {
        int b = (int)(r / Tm1); // one division per wave
        int t = (int)(r - (long)b * Tm1);

        // LDS write offsets for the exact path (padded layout)
        const int pad0 = lane * 4 + 8 * (lane >> 5);       // elems [0,256)
        const int pad1 = 272 + lane * 4 + 8 * (lane >> 5); // elems [256,512)

        nt_f4 v0, v1;
        {
            const float* row = x + ((long)b * Tv + t) * Dm + lane * 4;
            v0 = __builtin_nontemporal_load(reinterpret_cast<const nt_f4*>(row));
            v1 = __builtin_nontemporal_load(reinterpret_cast<const nt_f4*>(row + 256));
        }

        while (r < rend) {
            int bn = b, tn = t + 1;
            if (tn >= Tm1) { tn = 0; bn += 1; }
            const bool more = (r + 1) < rend;
            nt_f4 n0, n1;
            if (more) { // prefetch next row (issues before screen math)
                const float* row = x + ((long)bn * Tv + tn) * Dm + lane * 4;
                n0 = __builtin_nontemporal_load(reinterpret_cast<const nt_f4*>(row));
                n1 = __builtin_nontemporal_load(reinterpret_cast<const nt_f4*>(row + 256));
            }

            // ---- fast screen: order-free sum, one scale at the end ----
            float s = ((v0.x + v0.y) + (v0.z + v0.w)) +
                      ((v1.x + v1.y) + (v1.z + v1.w));
            s += __shfl_xor(s, 1);
            s += __shfl_xor(s, 2);
            s += __shfl_xor(s, 4);
            s += __shfl_xor(s, 8);
            s += __shfl_xor(s, 16);
            s += __shfl_xor(s, 32);
            s *= 1000.0f;
            const bool cand = fabsf(s - qf) <= 4.0f; // bound ~2.05, 2x margin
            const unsigned long long m = __ballot(cand);

            if (m) { // rare: exact numpy-order hash via LDS (wave-uniform)
                asm volatile("s_waitcnt lgkmcnt(0)" ::: "memory");
                *reinterpret_cast<nt_f4*>(&slab[wslab][pad0]) = v0;
                *reinterpret_cast<nt_f4*>(&slab[wslab][pad1]) = v1;
                asm volatile("s_waitcnt lgkmcnt(0)" ::: "memory");
                int h = hash_row_lds(slab[wslab], lane & 31);
                if (lane < Bv && h == qi) atomicMax(&best[lane], t * Bv + b);
            }

            if (more) { v0 = n0; v1 = n1; }
            b = bn; t = tn; ++r;
        }
    }

    // ---- done-counter barrier (release inc / acquire spin) ----
    __syncthreads(); // all waves' atomicMax drained (implies vmcnt(0))
    if (tid == 0)
        __hip_atomic_fetch_add(done, 1, __ATOMIC_RELEASE, __HIP_MEMORY_SCOPE_AGENT);

    const int b_out = (int)(blockIdx.x >> 3);
    if (blockIdx.x >= (unsigned)(Bv * 8)) return;

    if (tid == 0) {
        while (__hip_atomic_load(done, __ATOMIC_ACQUIRE, __HIP_MEMORY_SCOPE_AGENT) !=
               (int)gridDim.x)
            __builtin_amdgcn_s_sleep(2);
        sbest = __hip_atomic_load(&best[b_out], __ATOMIC_RELAXED, __HIP_MEMORY_SCOPE_AGENT);
    }
    __syncthreads();

    // ---- out part: out[b][d] = dot(W[d,:], retrieved) + bias[d] ----
    const int c = blockIdx.x & 7;
    const int w = tid >> 6, olane = tid & 63;
    const int idx = sbest;
    float r0, r1, r2, r3, r4, r5, r6, r7;
    if (idx >= 0) {
        int t = idx / Bv, bw = idx - (idx / Bv) * Bv; // n = t*B + b
        const float* row = x + ((long)bw * Tv + t) * Dm + olane * 8;
        float4 x0 = *reinterpret_cast<const float4*>(row);
        float4 x1 = *reinterpret_cast<const float4*>(row + 4);
        r0 = x0.x; r1 = x0.y; r2 = x0.z; r3 = x0.w;
        r4 = x1.x; r5 = x1.y; r6 = x1.z; r7 = x1.w;
    } else {
        r0 = r1 = r2 = r3 = r4 = r5 = r6 = r7 = 0.f;
    }
    for (int di = w; di < 64; di += 4) {
        int d = c * 64 + di;
        const float* wrow = W + (long)d * Dm + olane * 8;
        float4 w0 = *reinterpret_cast<const float4*>(wrow);
        float4 w1 = *reinterpret_cast<const float4*>(wrow + 4);
        float acc = w0.x * r0 + w0.y * r1 + w0.z * r2 + w0.w * r3 +
                    w1.x * r4 + w1.y * r5 + w1.z * r6 + w1.w * r7;
        acc += __shfl_xor(acc, 1);
        acc += __shfl_xor(acc, 2);
        acc += __shfl_xor(acc, 4);
        acc += __shfl_xor(acc, 8);
        acc += __shfl_xor(acc, 16);
        acc += __shfl_xor(acc, 32);
        if (olane == 0) out[(long)b_out * Dm + d] = acc + bias[d];
    }
}

extern "C" void kernel_launch(void* const* d_in, const int* in_sizes, int n_in,
                              void* d_out, int out_size, void* d_ws, size_t ws_size,
                              hipStream_t stream) {
    const float* x = (const float*)d_in[0];
    // d_in[1] = hx_list (unused by the reference)
    const float* W = (const float*)d_in[2];
    const float* bias = (const float*)d_in[3];
    float* out = (float*)d_out;

    int Bv = in_sizes[1];                 // 32
    long xs = (long)in_sizes[0];          // B*T*D
    int Tv = (int)(xs / ((long)Bv * Dm)); // 4096

    int* best = (int*)d_ws;               // [64]
    int* qh_i = (int*)d_ws + 64;          // [64]
    float* qh_f = (float*)d_ws + 128;     // [64]
    int* done = (int*)d_ws + 192;         // [1]

    init_kernel<<<1, 1024, 0, stream>>>(x, qh_i, qh_f, best, done, Bv, Tv);

    const int nblk = 2048;
    const long NR = (long)Bv * (Tv - 1);
    const int nwaves = nblk * 4;
    const int rpw = (int)((NR + nwaves - 1) / nwaves);
    fused_kernel<<<nblk, 256, 0, stream>>>(x, W, bias, qh_i, qh_f, best, done,
                                           out, Bv, Tv, rpw);
}

// Round 7
// 58.159 us; speedup vs baseline: 3.8021x; 3.8021x over previous
//
#include <hip/hip_runtime.h>

// B=32, T=4096, D=512. out[b] = retrieved[b] @ W.T + bias where retrieved[b]
// is the LAST write row (order n = t*B + b) whose int32 hash equals query b's
// hash. Hash = (int)trunc of numpy-pairwise f32 sum of row*1000 — bit-exact
// reproduction verified R1-R6.
//
// R7 = R5 structure (3 dispatches — R6's device-scope spin barrier caused L2
// maintenance storms on gfx950's non-coherent per-XCD L2s; reverted) plus:
//  - scale-once screen (sum raw, one *1000 after reduce; sound bound ~1.9,
//    eps=4.0 is >2x margin; exact numpy-order hash re-checks all candidates)
//  - parallel init (32 single-wave blocks, no serial multi-round hashing)

constexpr int Dm = 512;
constexpr int LROW = 544; // padded: elem idx stored at idx + 8*(idx>>7)

typedef float nt_f4 __attribute__((ext_vector_type(4))); // builtin-compatible

// Exact numpy pairwise sum of 512 f32 (each *1000 in f32 first), by a 32-lane
// group. lane=(k<<3)|j; k=128-block, j=accumulator. Per block: r[j] sequential
// 16 terms; combine ((r0+r1)+(r2+r3))+((r4+r5)+(r6+r7)); blocks (p0+p1)+(p2+p3).
// Butterfly == numpy tree (f32 add commutative). Bit-exact (R1 verified).
__device__ __forceinline__ int hash_row_lds(const float* rowp, int lane) {
#pragma clang fp contract(off)
    int k = lane >> 3, j = lane & 7;
    const float* p = rowp + k * 136 + j;
    float r = p[0] * 1000.0f;
#pragma unroll
    for (int i = 1; i < 16; ++i) {
        float prod = p[8 * i] * 1000.0f;
        r = r + prod;
    }
    r = r + __shfl_xor(r, 1);
    r = r + __shfl_xor(r, 2);
    r = r + __shfl_xor(r, 4);
    r = r + __shfl_xor(r, 8);
    r = r + __shfl_xor(r, 16);
    return (int)r; // trunc toward zero
}

// One query row per block (single wave). 64 lanes load the 2KB row into
// padded LDS; lanes 0-31 compute the exact hash. Block 0 also inits best[].
__global__ __launch_bounds__(64) void init_kernel(const float* __restrict__ x,
                                                  int* __restrict__ qh_i,
                                                  float* __restrict__ qh_f,
                                                  int* __restrict__ best,
                                                  int Bv, int Tv) {
    __shared__ float slab[LROW];
    const int lane = threadIdx.x;
    const int bq = blockIdx.x;
    if (bq == 0 && lane < Bv) best[lane] = -1;
    if (bq >= Bv) return;
    const float* row = x + ((long)bq * Tv + (Tv - 1)) * Dm;
    // lane loads elems [8L, 8L+8): both float4s stay inside one 128-block
    const int idx = lane * 8;
    const int off = idx + 8 * (idx >> 7);
    *reinterpret_cast<float4*>(&slab[off]) = *reinterpret_cast<const float4*>(row + idx);
    *reinterpret_cast<float4*>(&slab[off + 4]) = *reinterpret_cast<const float4*>(row + idx + 4);
    __syncthreads(); // single-wave: cheap, orders LDS writes before reads
    if (lane < 32) {
        int h = hash_row_lds(slab, lane);
        if (lane == 0) { qh_i[bq] = h; qh_f[bq] = (float)h; }
    }
}

// Wave-per-row streaming. Each wave owns rpw contiguous memory-order rows.
// Per iter: 2 x 1KB nontemporal loads (prefetched 1 row ahead), order-free
// screen sum (scale once after the 6-step butterfly), fixed-eps compare vs
// 32 query hashes. Flagged rows (~0.4%) take the exact LDS hash path.
__global__ __launch_bounds__(256) void stream_kernel(const float* __restrict__ x,
                                                     const int* __restrict__ qh_i,
                                                     const float* __restrict__ qh_f,
                                                     int* __restrict__ best,
                                                     int Bv, int Tv, int rpw) {
    __shared__ float slab[4][LROW];
    const int tid = threadIdx.x;
    const int wslab = tid >> 6;
    const int lane = tid & 63;
    const int Tm1 = Tv - 1;
    const long NR = (long)Bv * Tm1;

    int qi = (int)0x80000000;
    float qf = __builtin_inff();
    if (lane < Bv) { qi = qh_i[lane]; qf = qh_f[lane]; }

    const int wave_id = blockIdx.x * 4 + wslab;
    long r = (long)wave_id * rpw;
    const long rend = min(r + rpw, NR);
    if (r >= rend) return;

    int b = (int)(r / Tm1); // one division per wave
    int t = (int)(r - (long)b * Tm1);

    // LDS write offsets for the exact path (padded layout, see hash_row_lds)
    const int pad0 = lane * 4 + 8 * (lane >> 5);        // elems [0,256)
    const int pad1 = 272 + lane * 4 + 8 * (lane >> 5);  // elems [256,512)

    nt_f4 v0, v1;
    {
        const float* row = x + ((long)b * Tv + t) * Dm + lane * 4;
        v0 = __builtin_nontemporal_load(reinterpret_cast<const nt_f4*>(row));
        v1 = __builtin_nontemporal_load(reinterpret_cast<const nt_f4*>(row + 256));
    }

    while (r < rend) {
        int bn = b, tn = t + 1;
        if (tn >= Tm1) { tn = 0; bn += 1; }
        const bool more = (r + 1) < rend;
        nt_f4 n0, n1;
        if (more) { // prefetch next row (issues before screen math)
            const float* row = x + ((long)bn * Tv + tn) * Dm + lane * 4;
            n0 = __builtin_nontemporal_load(reinterpret_cast<const nt_f4*>(row));
            n1 = __builtin_nontemporal_load(reinterpret_cast<const nt_f4*>(row + 256));
        }

        // ---- fast screen: order-free raw sum, one scale at the end ----
        float s = ((v0.x + v0.y) + (v0.z + v0.w)) +
                  ((v1.x + v1.y) + (v1.z + v1.w));
        s += __shfl_xor(s, 1);
        s += __shfl_xor(s, 2);
        s += __shfl_xor(s, 4);
        s += __shfl_xor(s, 8);
        s += __shfl_xor(s, 16);
        s += __shfl_xor(s, 32);
        s *= 1000.0f;
        const bool cand = fabsf(s - qf) <= 4.0f; // sound bound ~1.9, >2x margin
        const unsigned long long m = __ballot(cand);

        if (m) { // rare: exact numpy-order hash via LDS (wave-uniform branch)
            asm volatile("s_waitcnt lgkmcnt(0)" ::: "memory");
            *reinterpret_cast<nt_f4*>(&slab[wslab][pad0]) = v0;
            *reinterpret_cast<nt_f4*>(&slab[wslab][pad1]) = v1;
            asm volatile("s_waitcnt lgkmcnt(0)" ::: "memory");
            int h = hash_row_lds(slab[wslab], lane & 31);
            if (lane < Bv && h == qi) atomicMax(&best[lane], t * Bv + b);
        }

        if (more) { v0 = n0; v1 = n1; }
        b = bn; t = tn; ++r;
    }
}

// out[b][d] = dot(W[d,:], retrieved) + bias[d]; 256 blocks = (b, 8 d-chunks).
__global__ __launch_bounds__(256) void out_kernel(const float* __restrict__ x,
                                                  const float* __restrict__ W,
                                                  const float* __restrict__ bias,
                                                  const int* __restrict__ best,
                                                  float* __restrict__ out,
                                                  int Bv, int Tv) {
    const int b = blockIdx.x >> 3;
    const int c = blockIdx.x & 7;
    const int w = threadIdx.x >> 6, lane = threadIdx.x & 63;
    const int idx = best[b];
    float r0, r1, r2, r3, r4, r5, r6, r7;
    if (idx >= 0) {
        int t = idx / Bv, bw = idx - (idx / Bv) * Bv; // n = t*B + b
        const float* row = x + ((long)bw * Tv + t) * Dm + lane * 8;
        float4 x0 = *reinterpret_cast<const float4*>(row);
        float4 x1 = *reinterpret_cast<const float4*>(row + 4);
        r0 = x0.x; r1 = x0.y; r2 = x0.z; r3 = x0.w;
        r4 = x1.x; r5 = x1.y; r6 = x1.z; r7 = x1.w;
    } else {
        r0 = r1 = r2 = r3 = r4 = r5 = r6 = r7 = 0.f;
    }
    for (int di = w; di < 64; di += 4) {
        int d = c * 64 + di;
        const float* wrow = W + (long)d * Dm + lane * 8;
        float4 w0 = *reinterpret_cast<const float4*>(wrow);
        float4 w1 = *reinterpret_cast<const float4*>(wrow + 4);
        float acc = w0.x * r0 + w0.y * r1 + w0.z * r2 + w0.w * r3 +
                    w1.x * r4 + w1.y * r5 + w1.z * r6 + w1.w * r7;
        acc += __shfl_xor(acc, 1);
        acc += __shfl_xor(acc, 2);
        acc += __shfl_xor(acc, 4);
        acc += __shfl_xor(acc, 8);
        acc += __shfl_xor(acc, 16);
        acc += __shfl_xor(acc, 32);
        if (lane == 0) out[(long)b * Dm + d] = acc + bias[d];
    }
}

extern "C" void kernel_launch(void* const* d_in, const int* in_sizes, int n_in,
                              void* d_out, int out_size, void* d_ws, size_t ws_size,
                              hipStream_t stream) {
    const float* x = (const float*)d_in[0];
    // d_in[1] = hx_list (unused by the reference)
    const float* W = (const float*)d_in[2];
    const float* bias = (const float*)d_in[3];
    float* out = (float*)d_out;

    int Bv = in_sizes[1];                 // 32
    long xs = (long)in_sizes[0];          // B*T*D
    int Tv = (int)(xs / ((long)Bv * Dm)); // 4096

    int* best = (int*)d_ws;               // [64]
    int* qh_i = (int*)d_ws + 64;          // [64]
    float* qh_f = (float*)d_ws + 128;     // [64]

    init_kernel<<<Bv, 64, 0, stream>>>(x, qh_i, qh_f, best, Bv, Tv);

    const int nblk = 2048;
    const long NR = (long)Bv * (Tv - 1);
    const int nwaves = nblk * 4;
    const int rpw = (int)((NR + nwaves - 1) / nwaves);
    stream_kernel<<<nblk, 256, 0, stream>>>(x, qh_i, qh_f, best, Bv, Tv, rpw);

    out_kernel<<<Bv * 8, 256, 0, stream>>>(x, W, bias, best, out, Bv, Tv);
}

// Round 8
// 57.677 us; speedup vs baseline: 3.8339x; 1.0084x over previous
//
#include <hip/hip_runtime.h>

// B=32, T=4096, D=512. out[b] = retrieved[b] @ W.T + bias where retrieved[b]
// is the LAST write row (order n = t*B + b) whose int32 hash equals query b's
// hash. Hash = (int)trunc of numpy-pairwise f32 sum of row*1000 — bit-exact
// reproduction verified R1-R7.
//
// R8: batched streaming — 8 rows per wave-iteration. Lane L owns row (L>>3),
// cols (L&7)*4 + c*32 (16 dwordx4 loads, immediate offsets, 16KB in flight).
// Per-lane sum of 64 floats + 3-step shfl within 8-lane groups (vs 6-step
// all-reduce PER ROW before: 3 shfls/8 rows instead of 48). Screen bound for
// this order: depth~11(fast)+19(numpy)+scale-once => err <= ~0.9 (+1 trunc
// window) < 2.0; eps=8.0 is 4x margin, ~0.9% flagged. Flagged rows re-read
// from global (L2/L3-warm, ~2KB each, rare) into the verified 64-lane LDS
// exact numpy-order hash path.

constexpr int Dm = 512;
constexpr int LROW = 544; // padded: elem idx stored at idx + 8*(idx>>7)

typedef float nt_f4 __attribute__((ext_vector_type(4))); // builtin-compatible

// Exact numpy pairwise sum of 512 f32 (each *1000 in f32 first), by a 32-lane
// group. lane=(k<<3)|j; k=128-block, j=accumulator. Per block: r[j] sequential
// 16 terms; combine ((r0+r1)+(r2+r3))+((r4+r5)+(r6+r7)); blocks (p0+p1)+(p2+p3).
// Butterfly == numpy tree (f32 add commutative). Bit-exact (R1 verified).
__device__ __forceinline__ int hash_row_lds(const float* rowp, int lane) {
#pragma clang fp contract(off)
    int k = lane >> 3, j = lane & 7;
    const float* p = rowp + k * 136 + j;
    float r = p[0] * 1000.0f;
#pragma unroll
    for (int i = 1; i < 16; ++i) {
        float prod = p[8 * i] * 1000.0f;
        r = r + prod;
    }
    r = r + __shfl_xor(r, 1);
    r = r + __shfl_xor(r, 2);
    r = r + __shfl_xor(r, 4);
    r = r + __shfl_xor(r, 8);
    r = r + __shfl_xor(r, 16);
    return (int)r; // trunc toward zero
}

// One query row per block (single wave). Block 0 also inits best[].
__global__ __launch_bounds__(64) void init_kernel(const float* __restrict__ x,
                                                  int* __restrict__ qh_i,
                                                  float* __restrict__ qh_f,
                                                  int* __restrict__ best,
                                                  int Bv, int Tv) {
    __shared__ float slab[LROW];
    const int lane = threadIdx.x;
    const int bq = blockIdx.x;
    if (bq == 0 && lane < Bv) best[lane] = -1;
    if (bq >= Bv) return;
    const float* row = x + ((long)bq * Tv + (Tv - 1)) * Dm;
    const int idx = lane * 8;
    const int off = idx + 8 * (idx >> 7);
    *reinterpret_cast<float4*>(&slab[off]) = *reinterpret_cast<const float4*>(row + idx);
    *reinterpret_cast<float4*>(&slab[off + 4]) = *reinterpret_cast<const float4*>(row + idx + 4);
    __syncthreads();
    if (lane < 32) {
        int h = hash_row_lds(slab, lane);
        if (lane == 0) { qh_i[bq] = h; qh_f[bq] = (float)h; }
    }
}

// Batched stream: each wave owns bpw batches of 8 consecutive memory-order
// rows. Exact path (rare) re-reads the flagged row with cached loads and runs
// the verified 64-lane staging + numpy-order hash.
__global__ __launch_bounds__(256) void stream_kernel(const float* __restrict__ x,
                                                     const int* __restrict__ qh_i,
                                                     const float* __restrict__ qh_f,
                                                     int* __restrict__ best,
                                                     int Bv, int Tv, int bpw) {
    __shared__ float slab[4][LROW];
    const int tid = threadIdx.x;
    const int wslab = tid >> 6;
    const int lane = tid & 63;
    const int g8 = lane & 7;    // column slot within 8-lane group
    const int rloc = lane >> 3; // row within batch
    const int Tm1 = Tv - 1;
    const long NR = (long)Bv * Tm1;
    const long NBat = (NR + 7) >> 3;

    int qi = (int)0x80000000;
    if (lane < Bv) qi = qh_i[lane];
    float qfv[4];
#pragma unroll
    for (int k = 0; k < 4; ++k) {
        int q = g8 * 4 + k;
        qfv[k] = (q < Bv) ? qh_f[q] : __builtin_inff();
    }

    // LDS offsets for the exact path (padded layout, see hash_row_lds)
    const int pad0 = lane * 4 + 8 * (lane >> 5);       // elems [0,256)
    const int pad1 = 272 + lane * 4 + 8 * (lane >> 5); // elems [256,512)

    const int wave_id = blockIdx.x * 4 + wslab;
    long bat = (long)wave_id * bpw;
    const long bend = min(bat + bpw, NBat);
    if (bat >= bend) return;

    long g0 = bat * 8;
    int b0 = (int)(g0 / Tm1); // one division per wave
    int t0 = (int)(g0 - (long)b0 * Tm1);

    while (bat < bend) {
        // this lane's row within the batch (batches can cross one b-boundary)
        const bool rv = (g0 + rloc) < NR;
        int tl = t0 + rloc, bl = b0;
        if (tl >= Tm1) { tl -= Tm1; bl += 1; }
        if (!rv) { tl = 0; bl = 0; } // safe dummy address
        const float* base = x + ((long)bl * Tv + tl) * Dm + g8 * 4;

        nt_f4 v[16];
#pragma unroll
        for (int c = 0; c < 16; ++c)
            v[c] = __builtin_nontemporal_load(reinterpret_cast<const nt_f4*>(base + c * 32));

        // per-lane sum of its 64 floats (4 independent accumulators)
        float a0 = 0.f, a1 = 0.f, a2 = 0.f, a3 = 0.f;
#pragma unroll
        for (int c = 0; c < 16; c += 4) {
            a0 += (v[c].x + v[c].y) + (v[c].z + v[c].w);
            a1 += (v[c + 1].x + v[c + 1].y) + (v[c + 1].z + v[c + 1].w);
            a2 += (v[c + 2].x + v[c + 2].y) + (v[c + 2].z + v[c + 2].w);
            a3 += (v[c + 3].x + v[c + 3].y) + (v[c + 3].z + v[c + 3].w);
        }
        float s = (a0 + a1) + (a2 + a3);
        s += __shfl_xor(s, 1); // 3-step reduce within the 8-lane group
        s += __shfl_xor(s, 2);
        s += __shfl_xor(s, 4);
        s *= 1000.0f;

        bool cand = rv && (fabsf(s - qfv[0]) <= 8.0f || fabsf(s - qfv[1]) <= 8.0f ||
                           fabsf(s - qfv[2]) <= 8.0f || fabsf(s - qfv[3]) <= 8.0f);
        const unsigned long long m = __ballot(cand);

        if (m) { // rare: exact numpy-order hash for each flagged row
            unsigned rmask = 0;
#pragma unroll
            for (int r = 0; r < 8; ++r)
                if ((m >> (8 * r)) & 0xFFull) rmask |= 1u << r;
            while (rmask) {
                const int r = __builtin_ctz(rmask);
                rmask &= rmask - 1;
                int tr = t0 + r, br = b0;
                if (tr >= Tm1) { tr -= Tm1; br += 1; }
                // whole wave re-reads the 2KB row (L2/L3-warm), stages padded
                const float* row = x + ((long)br * Tv + tr) * Dm + lane * 4;
                float4 w0 = *reinterpret_cast<const float4*>(row);
                float4 w1 = *reinterpret_cast<const float4*>(row + 256);
                asm volatile("s_waitcnt lgkmcnt(0)" ::: "memory");
                *reinterpret_cast<float4*>(&slab[wslab][pad0]) = w0;
                *reinterpret_cast<float4*>(&slab[wslab][pad1]) = w1;
                asm volatile("s_waitcnt lgkmcnt(0)" ::: "memory");
                int h = hash_row_lds(slab[wslab], lane & 31);
                if (lane < Bv && h == qi) atomicMax(&best[lane], tr * Bv + br);
            }
        }

        // advance to next batch of 8 rows
        t0 += 8;
        if (t0 >= Tm1) { t0 -= Tm1; b0 += 1; }
        g0 += 8;
        ++bat;
    }
}

// out[b][d] = dot(W[d,:], retrieved) + bias[d]; 256 blocks = (b, 8 d-chunks).
__global__ __launch_bounds__(256) void out_kernel(const float* __restrict__ x,
                                                  const float* __restrict__ W,
                                                  const float* __restrict__ bias,
                                                  const int* __restrict__ best,
                                                  float* __restrict__ out,
                                                  int Bv, int Tv) {
    const int b = blockIdx.x >> 3;
    const int c = blockIdx.x & 7;
    const int w = threadIdx.x >> 6, lane = threadIdx.x & 63;
    const int idx = best[b];
    float r0, r1, r2, r3, r4, r5, r6, r7;
    if (idx >= 0) {
        int t = idx / Bv, bw = idx - (idx / Bv) * Bv; // n = t*B + b
        const float* row = x + ((long)bw * Tv + t) * Dm + lane * 8;
        float4 x0 = *reinterpret_cast<const float4*>(row);
        float4 x1 = *reinterpret_cast<const float4*>(row + 4);
        r0 = x0.x; r1 = x0.y; r2 = x0.z; r3 = x0.w;
        r4 = x1.x; r5 = x1.y; r6 = x1.z; r7 = x1.w;
    } else {
        r0 = r1 = r2 = r3 = r4 = r5 = r6 = r7 = 0.f;
    }
    for (int di = w; di < 64; di += 4) {
        int d = c * 64 + di;
        const float* wrow = W + (long)d * Dm + lane * 8;
        float4 w0 = *reinterpret_cast<const float4*>(wrow);
        float4 w1 = *reinterpret_cast<const float4*>(wrow + 4);
        float acc = w0.x * r0 + w0.y * r1 + w0.z * r2 + w0.w * r3 +
                    w1.x * r4 + w1.y * r5 + w1.z * r6 + w1.w * r7;
        acc += __shfl_xor(acc, 1);
        acc += __shfl_xor(acc, 2);
        acc += __shfl_xor(acc, 4);
        acc += __shfl_xor(acc, 8);
        acc += __shfl_xor(acc, 16);
        acc += __shfl_xor(acc, 32);
        if (lane == 0) out[(long)b * Dm + d] = acc + bias[d];
    }
}

extern "C" void kernel_launch(void* const* d_in, const int* in_sizes, int n_in,
                              void* d_out, int out_size, void* d_ws, size_t ws_size,
                              hipStream_t stream) {
    const float* x = (const float*)d_in[0];
    // d_in[1] = hx_list (unused by the reference)
    const float* W = (const float*)d_in[2];
    const float* bias = (const float*)d_in[3];
    float* out = (float*)d_out;

    int Bv = in_sizes[1];                 // 32
    long xs = (long)in_sizes[0];          // B*T*D
    int Tv = (int)(xs / ((long)Bv * Dm)); // 4096

    int* best = (int*)d_ws;               // [64]
    int* qh_i = (int*)d_ws + 64;          // [64]
    float* qh_f = (float*)d_ws + 128;     // [64]

    init_kernel<<<Bv, 64, 0, stream>>>(x, qh_i, qh_f, best, Bv, Tv);

    const int nblk = 2048;
    const long NR = (long)Bv * (Tv - 1);
    const long NBat = (NR + 7) >> 3;
    const int nwaves = nblk * 4;
    const int bpw = (int)((NBat + nwaves - 1) / nwaves);
    stream_kernel<<<nblk, 256, 0, stream>>>(x, qh_i, qh_f, best, Bv, Tv, bpw);

    out_kernel<<<Bv * 8, 256, 0, stream>>>(x, W, bias, best, out, Bv, Tv);
}